// Round 1
// 1175.653 us; speedup vs baseline: 1.3806x; 1.3806x over previous
//
#include <hip/hip_runtime.h>

#define NB 32
#define TT 2048
#define II 256
#define HH 512
#define LCH 8
#define NCH 256

typedef short s8v __attribute__((ext_vector_type(8)));
typedef short s4v __attribute__((ext_vector_type(4)));
typedef __bf16 bf8v __attribute__((ext_vector_type(8)));
typedef float f4v __attribute__((ext_vector_type(4)));

#define DEVI static __device__ __forceinline__

DEVI float bf2f(short s){ union{unsigned u; float f;} c; c.u = ((unsigned)(unsigned short)s) << 16; return c.f; }
DEVI short f2bf(float f){ union{float f; unsigned u;} c; c.f = f; unsigned u = c.u; u += 0x7FFF + ((u >> 16) & 1); return (short)(u >> 16); }
DEVI f4v fzero(){ f4v z = {0.0f,0.0f,0.0f,0.0f}; return z; }

DEVI f4v mfma16(s8v a, s8v b, f4v c){
  union{ s8v s; bf8v b; } ua, ub; ua.s = a; ub.s = b;
  return __builtin_amdgcn_mfma_f32_16x16x32_bf16(ua.b, ub.b, c, 0, 0, 0);
}

// A-frag / B^T-frag from global: lane holds M[row0 + (lane&15)][k0 + (lane>>4)*8 + 0..7]
DEVI s8v ldfrag_bf(const short* base, int row0, int ld, int k0, int lane){
  const short* p = base + (size_t)(row0 + (lane & 15)) * ld + k0 + ((lane >> 4) << 3);
  return *(const s8v*)p;
}
DEVI s8v ldfrag_f32(const float* base, int row0, int ld, int k0, int lane){
  const float* p = base + (size_t)(row0 + (lane & 15)) * ld + k0 + ((lane >> 4) << 3);
  f4v lo = *(const f4v*)p;
  f4v hi = *(const f4v*)(p + 4);
  s8v o;
  o[0]=f2bf(lo[0]); o[1]=f2bf(lo[1]); o[2]=f2bf(lo[2]); o[3]=f2bf(lo[3]);
  o[4]=f2bf(hi[0]); o[5]=f2bf(hi[1]); o[6]=f2bf(hi[2]); o[7]=f2bf(hi[3]);
  return o;
}

// XOR swizzle for LDS state buffer (row stride 512 bf16 = 1024 B)
DEVI int swzoff(int row, int col){ return (row << 9) + ((((col >> 3) ^ (row & 7)) << 3) | (col & 7)); }

// lgkm-only barrier: does NOT drain vmcnt, so global stores / loads stay in flight
#define RAWBAR() asm volatile("s_waitcnt lgkmcnt(0)\n\ts_barrier" ::: "memory")

DEVI void gload16(const void* g, void* l){
  __builtin_amdgcn_global_load_lds((const __attribute__((address_space(1))) void*)g,
                                   (__attribute__((address_space(3))) void*)l, 16, 0, 0);
}

// Stage one K-chunk of Bt[512][ld] (cols 0..511, k in [k0,k0+64)) into btile[512][64],
// group-XOR-swizzled so frag ds_read_b128 spreads banks. gload_lds writes LDS linearly,
// so the swizzle is applied by permuting the SOURCE k-group per lane (involution).
DEVI void stageB(const short* Bt, int ld, int k0, short* btile, int wave, int lane){
  #pragma unroll
  for(int r = 0; r < 8; ++r){
    int slotbase = (((r << 3) + wave) << 6);   // 16B-slot base for this wave-round
    int slot = slotbase + lane;
    int col = slot >> 3, g = slot & 7;
    int gsrc = g ^ (col & 7);
    gload16(Bt + (size_t)col * ld + k0 + (gsrc << 3), btile + ((size_t)slotbase << 3));
  }
}

// read B-frag for output col `col`, k-offset kk (0/32) from swizzled btile
DEVI s8v ldB(const short* btile, int col, int q, int kk){
  int gphys = ((kk >> 3) + q) ^ (col & 7);
  return *(const s8v*)(btile + (col << 6) + (gphys << 3));
}

// ---------------- fp32 W_hh -> bf16 mats[0] + transpose matsT[0] ----------------
__global__ __launch_bounds__(256) void k_init_p1(const float* __restrict__ W,
                                                 short* __restrict__ mats, short* __restrict__ matsT){
  __shared__ short tile[64][65];
  int bx = blockIdx.x, by = blockIdx.y;
  int t = threadIdx.x;
  for(int i = 0; i < 16; ++i){
    int idx = t + 256*i;
    int rr = idx >> 6, cc = idx & 63;
    short v = f2bf(W[(size_t)(64*by + rr)*HH + 64*bx + cc]);
    tile[rr][cc] = v;
    mats[(size_t)(64*by + rr)*HH + 64*bx + cc] = v;
  }
  __syncthreads();
  for(int i = 0; i < 16; ++i){
    int idx = t + 256*i;
    int rr = idx >> 6, cc = idx & 63;
    matsT[(size_t)(64*bx + rr)*HH + 64*by + cc] = tile[cc][rr];
  }
}

// ---------------- fp32 -> bf16 elementwise (for W_ih) ----------------
__global__ __launch_bounds__(256) void k_cvt(const float* __restrict__ src, short* __restrict__ dst, int n){
  for(int i = blockIdx.x*256 + threadIdx.x; i < n; i += gridDim.x*256) dst[i] = f2bf(src[i]);
}

// ---------------- bf16 512x512 product C = A*B (Bt given), writes C and C^T ----------------
struct ProdArgs {
  const short* A[8]; const short* Bt[8]; short* C[8]; short* Ct[8];
};
__global__ __launch_bounds__(256) void k_prod(ProdArgs args){
  int bz = blockIdx.z;
  const short* A  = args.A[bz];
  const short* Bt = args.Bt[bz];
  short* C  = args.C[bz];
  short* Ct = args.Ct[bz];
  int wave = threadIdx.x >> 6, lane = threadIdx.x & 63;
  int mrow0 = blockIdx.x*64 + (wave & 1)*32;
  int ncol0 = blockIdx.y*128 + (wave >> 1)*64;
  f4v acc[2][4];
  for(int mi=0;mi<2;mi++) for(int j=0;j<4;j++) acc[mi][j] = fzero();
  for(int k0 = 0; k0 < HH; k0 += 32){
    s8v a0 = ldfrag_bf(A, mrow0,      HH, k0, lane);
    s8v a1 = ldfrag_bf(A, mrow0 + 16, HH, k0, lane);
    #pragma unroll
    for(int j = 0; j < 4; ++j){
      s8v b = ldfrag_bf(Bt, ncol0 + (j<<4), HH, k0, lane);
      acc[0][j] = mfma16(a0, b, acc[0][j]);
      acc[1][j] = mfma16(a1, b, acc[1][j]);
    }
  }
  int q = lane >> 4, c0 = lane & 15;
  for(int mi=0;mi<2;mi++) for(int j=0;j<4;j++) for(int r=0;r<4;r++){
    int row = mrow0 + (mi<<4) + (q<<2) + r;
    int col = ncol0 + (j<<4) + c0;
    short v = f2bf(acc[mi][j][r]);
    C [(size_t)row*HH + col] = v;
    Ct[(size_t)col*HH + row] = v;
  }
}

// ---------------- proj = x @ W_ih^T + b_ih (bf16 out); h0 = initial + proj[:,0] -> Y0[0] ----------------
// staged-B version: one 32-row tile per block (x read exactly once), coalesced bf16 output via LDS
__global__ __launch_bounds__(512, 4) void k_proj(const float* __restrict__ x, const short* __restrict__ Wb,
                                                 const float* __restrict__ bih, const float* __restrict__ initial,
                                                 short* __restrict__ projb, float* __restrict__ Y00){
  __shared__ __align__(16) short btile[HH*64];
  int b = blockIdx.x;                          // rows 32b .. 32b+31 (row = n*2048 + t)
  int tid = threadIdx.x, wave = tid >> 6, lane = tid & 63;
  int q = lane >> 4, c0 = lane & 15;
  int ncol0 = wave << 6;
  int mrow0 = b << 5;
  f4v acc[2][4];
  #pragma unroll
  for(int mi=0;mi<2;mi++)
  #pragma unroll
  for(int j=0;j<4;j++) acc[mi][j] = fzero();
  s8v a[2][2], an[2][2];
  #pragma unroll
  for(int mi=0;mi<2;++mi)
  #pragma unroll
  for(int k2=0;k2<2;++k2) a[mi][k2] = ldfrag_f32(x, mrow0 + (mi<<4), II, (k2<<5), lane);
  for(int kc = 0; kc < 4; ++kc){
    stageB(Wb, II, kc << 6, btile, wave, lane);
    if(kc < 3){
      #pragma unroll
      for(int mi=0;mi<2;++mi)
      #pragma unroll
      for(int k2=0;k2<2;++k2) an[mi][k2] = ldfrag_f32(x, mrow0 + (mi<<4), II, ((kc+1)<<6)+(k2<<5), lane);
    }
    __syncthreads();
    #pragma unroll
    for(int k2 = 0; k2 < 2; ++k2){
      int kk = k2 << 5;
      #pragma unroll
      for(int j = 0; j < 4; ++j){
        s8v bb = ldB(btile, ncol0 + (j<<4) + c0, q, kk);
        acc[0][j] = mfma16(a[0][k2], bb, acc[0][j]);
        acc[1][j] = mfma16(a[1][k2], bb, acc[1][j]);
      }
    }
    RAWBAR();
    #pragma unroll
    for(int mi=0;mi<2;++mi)
    #pragma unroll
    for(int k2=0;k2<2;++k2) a[mi][k2] = an[mi][k2];
  }
  short* pstage = btile;                        // 32x512 bf16 stage (aliases btile, reads done)
  #pragma unroll
  for(int mi=0;mi<2;++mi)
  #pragma unroll
  for(int j=0;j<4;++j)
  #pragma unroll
  for(int r=0;r<4;++r){
    int rown = (mi<<4) + (q<<2) + r;
    int col  = ncol0 + (j<<4) + c0;
    float v = acc[mi][j][r] + bih[col];
    pstage[rown*HH + col] = f2bf(v);
    if(((b & 63) | rown) == 0){                 // global row = n*2048 (t==0)
      int n = mrow0 >> 11;
      Y00[(size_t)n*HH + col] = v + initial[(size_t)n*HH + col];
    }
  }
  RAWBAR();
  #pragma unroll
  for(int rr = 0; rr < 4; ++rr){                // coalesced 16B stores, full lines
    int si = tid + (rr << 9);
    int rn = si >> 6, u = (si & 63) << 3;
    *(s8v*)(projb + ((size_t)(mrow0 + rn))*HH + u) = *(const s8v*)(pstage + rn*HH + u);
  }
}

// ---------------- chunked scan, staged-B. PHASE 0: zero-init, emit chunk summaries Y0[c+1].
// PHASE 1: init from true boundary state Zin[c], write final hiddens to Yout (=out1). ----------------
template<int PHASE>
__global__ __launch_bounds__(512, 2) void k_scan(const short* __restrict__ projb,
                                                 const short* __restrict__ Wb,
                                                 const float* __restrict__ Zin,
                                                 float* __restrict__ Yout){
  __shared__ __align__(16) short btile[HH*64];   // 64KB W k-chunk; PHASE1: aliased as fp32 out-stage
  __shared__ __align__(16) short st[NB*HH];      // 32KB bf16 state (swizzled)
  __shared__ __align__(16) short pbuf[NB*HH];    // 32KB proj staging (linear [32][512])
  int c = blockIdx.x;
  int tid = threadIdx.x, wave = tid >> 6, lane = tid & 63;
  int q = lane >> 4, c0 = lane & 15;
  int ncol0 = wave << 6;
  float* fstage = (float*)btile;
  if(PHASE == 0){
    for(int i = tid; i < NB*HH; i += 512) st[i] = 0;
  } else {
    const float* Z = Zin + (size_t)c*NB*HH;
    #pragma unroll
    for(int rr = 0; rr < 8; ++rr){
      int fi = tid + (rr << 9);
      int rn = fi >> 7, col = (fi & 127) << 2;
      f4v v = *(const f4v*)(Z + (size_t)rn*HH + col);
      s4v sv; sv[0]=f2bf(v[0]); sv[1]=f2bf(v[1]); sv[2]=f2bf(v[2]); sv[3]=f2bf(v[3]);
      *(s4v*)(st + swzoff(rn, col)) = sv;
      if(c == 0) *(f4v*)(Yout + ((size_t)rn*TT)*HH + col) = v;   // t = 0 slice
    }
  }
  RAWBAR();
  int tmax = min(LCH, TT - 1 - LCH*c);
  for(int tl = 1; tl <= tmax; ++tl){
    int t = LCH*c + tl;
    // async-stage this step's proj rows (consumed in epilogue, latency hidden under K-loop)
    #pragma unroll
    for(int r = 0; r < 4; ++r){
      int rn = wave + (r << 3);
      gload16(projb + ((size_t)rn*TT + (t-1))*HH + ((size_t)lane << 3), pbuf + rn*HH);
    }
    f4v acc[2][4];
    #pragma unroll
    for(int mi=0;mi<2;mi++)
    #pragma unroll
    for(int j=0;j<4;j++) acc[mi][j] = fzero();
    for(int kc = 0; kc < 8; ++kc){
      stageB(Wb, HH, kc << 6, btile, wave, lane);
      __syncthreads();
      #pragma unroll
      for(int k2 = 0; k2 < 2; ++k2){
        int kk = k2 << 5;
        int colb = (kc << 6) + kk + (q << 3);
        s8v a0 = *(const s8v*)(st + swzoff(c0,      colb));
        s8v a1 = *(const s8v*)(st + swzoff(c0 + 16, colb));
        #pragma unroll
        for(int j = 0; j < 4; ++j){
          s8v bb = ldB(btile, ncol0 + (j<<4) + c0, q, kk);
          acc[0][j] = mfma16(a0, bb, acc[0][j]);
          acc[1][j] = mfma16(a1, bb, acc[1][j]);
        }
      }
      RAWBAR();                                  // btile reads done -> safe to restage
    }
    // epilogue: s_new = acc + p  (fp32); update bf16 state in-place (all reads completed)
    #pragma unroll
    for(int mi=0;mi<2;++mi)
    #pragma unroll
    for(int j=0;j<4;++j)
    #pragma unroll
    for(int r=0;r<4;++r){
      int rown = (mi<<4) + (q<<2) + r;
      int col  = ncol0 + (j<<4) + c0;
      float v = acc[mi][j][r] + bf2f(pbuf[rown*HH + col]);
      st[swzoff(rown, col)] = f2bf(v);
      if(PHASE == 0){
        if(tl == LCH && c + 1 < NCH)
          Yout[((size_t)(c+1)*NB + rown)*HH + col] = v;   // chunk summary
      } else {
        fstage[rown*HH + col] = v;
      }
    }
    if(PHASE == 1){
      RAWBAR();
      #pragma unroll
      for(int rr = 0; rr < 8; ++rr){            // coalesced full-line f4v stores; drain deferred
        int fi = tid + (rr << 9);
        int rn = fi >> 7, col = (fi & 127) << 2;
        *(f4v*)(Yout + ((size_t)rn*TT + t)*HH + col) = *(const f4v*)(fstage + (size_t)rn*HH + col);
      }
    }
    RAWBAR();
  }
}

// ---------------- Kogge-Stone level: Yout[i] = Yin[i] + Yin[i-s] @ As^T (staged-B) ----------------
__global__ __launch_bounds__(512, 2) void k_ks(const float* __restrict__ Yin, float* __restrict__ Yout,
                                               const short* __restrict__ As, int s){
  __shared__ __align__(16) short btile[HH*64];
  int i = blockIdx.x;
  int tid = threadIdx.x;
  if(i < s){
    const float* src = Yin + (size_t)i*NB*HH;
    float* dst = Yout + (size_t)i*NB*HH;
    for(int fi = tid; fi < NB*HH/4; fi += 512)
      *(f4v*)(dst + ((size_t)fi << 2)) = *(const f4v*)(src + ((size_t)fi << 2));
    return;
  }
  int wave = tid >> 6, lane = tid & 63;
  int q = lane >> 4, c0 = lane & 15;
  int ncol0 = wave << 6;
  const float* Xp = Yin + (size_t)(i - s)*NB*HH;
  const float* Xc = Yin + (size_t)i*NB*HH;
  float* Out = Yout + (size_t)i*NB*HH;
  f4v acc[2][4];
  #pragma unroll
  for(int mi=0;mi<2;mi++)
  #pragma unroll
  for(int j=0;j<4;j++) acc[mi][j] = fzero();
  s8v a[2], an[2];
  a[0] = ldfrag_f32(Xp, 0,  HH, 0, lane);
  a[1] = ldfrag_f32(Xp, 16, HH, 0, lane);
  for(int kc = 0; kc < 8; ++kc){
    stageB(As, HH, kc << 6, btile, wave, lane);
    __syncthreads();
    #pragma unroll
    for(int k2 = 0; k2 < 2; ++k2){
      int kk = k2 << 5;
      int k0n = (kc << 6) + kk + 32;
      if(k0n < HH){
        an[0] = ldfrag_f32(Xp, 0,  HH, k0n, lane);
        an[1] = ldfrag_f32(Xp, 16, HH, k0n, lane);
      }
      #pragma unroll
      for(int j = 0; j < 4; ++j){
        s8v bb = ldB(btile, ncol0 + (j<<4) + c0, q, kk);
        acc[0][j] = mfma16(a[0], bb, acc[0][j]);
        acc[1][j] = mfma16(a[1], bb, acc[1][j]);
      }
      a[0] = an[0]; a[1] = an[1];
    }
    RAWBAR();
  }
  #pragma unroll
  for(int mi=0;mi<2;++mi)
  #pragma unroll
  for(int j=0;j<4;++j)
  #pragma unroll
  for(int r=0;r<4;++r){
    int rown = (mi<<4) + (q<<2) + r;
    int col  = ncol0 + (j<<4) + c0;
    Out[(size_t)rown*HH + col] = acc[mi][j][r] + Xc[(size_t)rown*HH + col];
  }
}

// ---------------- out2 = out1 ----------------
__global__ __launch_bounds__(256) void k_dup(const float* __restrict__ a, float* __restrict__ b, int n4){
  for(int i = blockIdx.x*256 + threadIdx.x; i < n4; i += gridDim.x*256)
    ((f4v*)b)[i] = ((const f4v*)a)[i];
}

extern "C" void kernel_launch(void* const* d_in, const int* in_sizes, int n_in,
                              void* d_out, int out_size, void* d_ws, size_t ws_size,
                              hipStream_t stream) {
  const float* x       = (const float*)d_in[0];  // [32,2048,256] fp32
  const float* initial = (const float*)d_in[1];  // [32,512]
  const float* Wih     = (const float*)d_in[2];  // [512,256]
  const float* bih     = (const float*)d_in[3];  // [512]
  const float* Whh     = (const float*)d_in[4];  // [512,512]
  float* out1 = (float*)d_out;
  float* out2 = out1 + (size_t)NB*TT*HH;
  short* projb = (short*)out2;                   // bf16 proj scratch inside copy-2 region
                                                 // (out2 produced last by k_dup -> no aliasing hazard)

  const size_t MSZ = (size_t)HH*HH;
  short* mats  = (short*)d_ws;                   // 11 slots: W^(2^i), i=0..10
  short* matsT = mats + 11*MSZ;
  short* Wihb  = matsT + 11*MSZ;                 // [512,256] bf16
  float* Y0 = (float*)(Wihb + (size_t)HH*II);    // NCH boundary states [256][32][512] fp32
  float* Y1 = out1;                              // KS ping-pong scratch aliases out1 (used pre-scan2 only)

  auto M = [&](int i){ return mats  + (size_t)i*MSZ; };
  auto T = [&](int i){ return matsT + (size_t)i*MSZ; };

  k_init_p1<<<dim3(8,8), 256, 0, stream>>>(Whh, M(0), T(0));
  k_cvt<<<dim3(64), 256, 0, stream>>>(Wih, Wihb, HH*II);

  // squaring chain: M(i+1) = M(i)^2  ->  W^2, W^4, ..., W^1024
  ProdArgs pa;
  for(int i = 0; i < 10; ++i){
    pa.A[0] = M(i); pa.Bt[0] = T(i); pa.C[0] = M(i+1); pa.Ct[0] = T(i+1);
    k_prod<<<dim3(8,4,1), 256, 0, stream>>>(pa);
  }

  k_proj<<<dim3(2048), 512, 0, stream>>>(x, Wihb, bih, initial, projb, Y0);   // projb + Y0[0]=h0
  k_scan<0><<<dim3(NCH), 512, 0, stream>>>(projb, M(0), nullptr, Y0);         // summaries Y0[1..255]

  // Kogge-Stone over 256 boundary states: level l uses A^s = W^(8*2^l) = M(3+l)
  float* Ya = Y0; float* Yb = Y1;
  for(int l = 0; l < 8; ++l){
    k_ks<<<dim3(NCH), 512, 0, stream>>>(Ya, Yb, M(3 + l), 1 << l);
    float* tsw = Ya; Ya = Yb; Yb = tsw;
  }
  // 8 swaps -> final boundary states in Y0

  k_scan<1><<<dim3(NCH), 512, 0, stream>>>(projb, M(0), Y0, out1);            // final hiddens -> out1
  k_dup<<<dim3(2048), 256, 0, stream>>>(out1, out2, NB*TT*HH/4);              // out2 = out1
}